// Round 5
// baseline (430.386 us; speedup 1.0000x reference)
//
#include <hip/hip_runtime.h>
#include <hip/hip_bf16.h>

#define NEG_SLOPE 0.01f
#define C 128
#define NGRAPH 64

typedef short short8 __attribute__((ext_vector_type(8)));
typedef float f32x4 __attribute__((ext_vector_type(4)));

// monotone float <-> uint mapping for atomicMax-based segment max
__device__ __forceinline__ unsigned fmap(float x){
  unsigned b = __float_as_uint(x);
  return (b & 0x80000000u) ? ~b : (b | 0x80000000u);
}
__device__ __forceinline__ float funmap(unsigned k){
  return (k & 0x80000000u) ? __uint_as_float(k & 0x7FFFFFFFu) : __uint_as_float(~k);
}

// round-to-nearest-even bf16
__device__ __forceinline__ unsigned short bf16_rne(float a){
  unsigned u = __float_as_uint(a);
  return (unsigned short)((u + 0x7FFFu + ((u >> 16) & 1u)) >> 16);
}
// split fp32 into bf16 hi (RNE) + bf16 lo (residual); a ~= hi + lo, err ~2^-17
__device__ __forceinline__ void split2_bf16(float a, unsigned short& hi, unsigned short& lo){
  hi = bf16_rne(a);
  float r = a - __uint_as_float(((unsigned)hi) << 16);
  lo = bf16_rne(r);
}
__device__ __forceinline__ float bf16_to_f32(unsigned short h){
  return __uint_as_float(((unsigned)h) << 16);
}

// ---------- one-time fp32 -> bf16 hi/lo plane split (layer-1 x) ----------
__global__ void split_plane(const float* __restrict__ in, short* __restrict__ hi,
                            short* __restrict__ lo, int n){
  int i = (blockIdx.x * blockDim.x + threadIdx.x) * 2;
  if(i >= n) return;
  float2 v = *(const float2*)(in + i);
  unsigned short h0, l0, h1, l1;
  split2_bf16(v.x, h0, l0);
  split2_bf16(v.y, h1, l1);
  *(ushort2*)(hi + i) = make_ushort2(h0, h1);
  *(ushort2*)(lo + i) = make_ushort2(l0, l1);
}

// ---------- CSR build ----------
__global__ void deg_kernel(const int* __restrict__ dst, int* __restrict__ deg, int E){
  int e = blockIdx.x * blockDim.x + threadIdx.x;
  if(e < E) atomicAdd(&deg[dst[e]], 1);
}

__global__ void scan_block(const int* __restrict__ deg, int* __restrict__ incl,
                           int* __restrict__ bsum, int N){
  __shared__ int sm[1024];
  int t = threadIdx.x;
  int i = blockIdx.x * 1024 + t;
  int v = (i < N) ? deg[i] : 0;
  sm[t] = v;
  __syncthreads();
  for(int off = 1; off < 1024; off <<= 1){
    int a = (t >= off) ? sm[t - off] : 0;
    __syncthreads();
    sm[t] += a;
    __syncthreads();
  }
  if(i < N) incl[i] = sm[t];
  if(t == 1023) bsum[blockIdx.x] = sm[t];
}

__global__ void scan_bsum(const int* __restrict__ bsum, int* __restrict__ boff, int nb){
  __shared__ int sm[64];
  int t = threadIdx.x;
  sm[t] = (t < nb) ? bsum[t] : 0;
  __syncthreads();
  for(int off = 1; off < 64; off <<= 1){
    int a = (t >= off) ? sm[t - off] : 0;
    __syncthreads();
    sm[t] += a;
    __syncthreads();
  }
  if(t < nb) boff[t] = sm[t] - bsum[t];
}

// rows[i] = exclusive prefix; also produce inv_deg
__global__ void finalize_rows(const int* __restrict__ incl, const int* __restrict__ deg,
                              const int* __restrict__ boff, int* __restrict__ rows,
                              float* __restrict__ inv_deg, int N, int E){
  int i = blockIdx.x * blockDim.x + threadIdx.x;
  if(i < N){
    rows[i] = incl[i] - deg[i] + boff[i >> 10];
    inv_deg[i] = 1.0f / fmaxf((float)deg[i], 1.0f);
  }
  if(i == 0) rows[N] = E;
}

__global__ void csr_fill_kernel(const int* __restrict__ src, const int* __restrict__ dst,
                                const int* __restrict__ row_start, int* __restrict__ cursor,
                                int* __restrict__ csr, int E){
  int e = blockIdx.x * blockDim.x + threadIdx.x;
  if(e >= E) return;
  int d = dst[e];
  int p = atomicAdd(&cursor[d], 1);
  csr[row_start[d] + p] = src[e];
}

// ---------- aggregation: one wave per node, gather bf16-hi plane, write mean hi/lo ----------
__global__ __launch_bounds__(256) void agg_csr_bf16(
    const short* __restrict__ xhi, const int* __restrict__ csr,
    const int* __restrict__ row_start, const float* __restrict__ inv_deg,
    short* __restrict__ mhi, short* __restrict__ mlo, int N)
{
  int node = blockIdx.x * 4 + (threadIdx.x >> 6);
  if(node >= N) return;
  int lane = threadIdx.x & 63;
  int beg = row_start[node], end = row_start[node + 1];
  float a0 = 0.f, a1 = 0.f;
  for(int base = beg; base < end; base += 64){
    int cnt = end - base; if(cnt > 64) cnt = 64;
    int s_l = (base + lane < end) ? csr[base + lane] : 0;
    for(int j = 0; j < cnt; j++){
      int s = __shfl(s_l, j, 64);
      ushort2 v = *(const ushort2*)(xhi + (long long)s * C + lane * 2);
      a0 += bf16_to_f32(v.x);
      a1 += bf16_to_f32(v.y);
    }
  }
  float sc = inv_deg[node];
  a0 *= sc; a1 *= sc;
  unsigned short h0, l0, h1, l1;
  split2_bf16(a0, h0, l0);
  split2_bf16(a1, h1, l1);
  *(ushort2*)(mhi + (long long)node * C + lane * 2) = make_ushort2(h0, h1);
  *(ushort2*)(mlo + (long long)node * C + lane * 2) = make_ushort2(l0, l1);
}

// ---------- weight pre-pack into MFMA B-fragment layout, bf16 hi/lo ----------
// B = [W_l ; W_r] (256 x 128).  frag index: (((kstep*4 + kg)*128 + n)*8 + j)
// where k = kstep*32 + kg*8 + j.  hi at [0 .. 32767], lo at [32768 ..].
__global__ void pack_kernel(const float* __restrict__ Wl, const float* __restrict__ Wr,
                            short* __restrict__ Bpk){
  int idx = blockIdx.x * blockDim.x + threadIdx.x;   // 0 .. 32767
  if(idx >= 2 * C * C) return;
  int k = idx >> 7, n = idx & 127;
  float w = (k < C) ? Wl[k * C + n] : Wr[(k - C) * C + n];
  unsigned short hi, lo;
  split2_bf16(w, hi, lo);
  int kstep = k >> 5, kg = (k >> 3) & 3, j = k & 7;
  int pos = ((kstep * 4 + kg) * C + n) * 8 + j;
  Bpk[pos] = (short)hi;
  Bpk[pos + 32768] = (short)lo;
}

// ---------- MFMA GEMM, no LDS: h = leakyrelu([mean | x] @ B + bias) ----------
// A operands are pre-split bf16 hi/lo planes, loaded straight into MFMA A-layout
// (A[m=lane&15][k=(lane>>4)*8+j], 16 B/lane). 3 MFMA passes:
// Ahi*Bhi + Alo*Bhi + Ahi*Blo (~fp32 accuracy).
// Block: 128 rows x 128 cols, 4 waves 2x2, wave tile 64x64.
// pooled != nullptr (last layer): fused global-max-pool epilogue, no h store.
__global__ __launch_bounds__(256) void gemm_mfma2(
    const short* __restrict__ Amh, const short* __restrict__ Aml,
    const short* __restrict__ Axh, const short* __restrict__ Axl,
    const short* __restrict__ Bpk, const float* __restrict__ bias,
    short* __restrict__ Hhi, short* __restrict__ Hlo, int M,
    const int* __restrict__ batch, unsigned* __restrict__ pooled)
{
  int tid = threadIdx.x;
  int bm = blockIdx.x * 128;
  int lane = tid & 63;
  int wave = tid >> 6;
  int wm = wave >> 1, wn = wave & 1;
  int lg = lane >> 4;        // k-group (A/B), row-group (C/D)
  int lm = lane & 15;        // m (A) / n (B) / col (C/D)

  f32x4 acc[4][4];
#pragma unroll
  for(int i = 0; i < 4; i++)
#pragma unroll
    for(int j = 0; j < 4; j++)
      acc[i][j] = (f32x4){0.f, 0.f, 0.f, 0.f};

  const short8 zfrag = {0, 0, 0, 0, 0, 0, 0, 0};

  for(int ks = 0; ks < 8; ks++){
    const short* ph = (ks < 4) ? Amh : Axh;
    const short* pl = (ks < 4) ? Aml : Axl;
    int kcol = (ks & 3) * 32 + lg * 8;

    short8 bh[4], bl[4], ah[4], al[4];
#pragma unroll
    for(int j = 0; j < 4; j++){
      const short* bp = Bpk + (((ks * 4 + lg) * C) + wn * 64 + j * 16 + lm) * 8;
      bh[j] = *(const short8*)bp;
      bl[j] = *(const short8*)(bp + 32768);
    }
#pragma unroll
    for(int i = 0; i < 4; i++){
      int row = bm + wm * 64 + i * 16 + lm;
      if(row < M){
        const long long o = (long long)row * C + kcol;
        ah[i] = *(const short8*)(ph + o);
        al[i] = *(const short8*)(pl + o);
      }else{
        ah[i] = zfrag;
        al[i] = zfrag;
      }
    }
#pragma unroll
    for(int i = 0; i < 4; i++)
#pragma unroll
      for(int j = 0; j < 4; j++){
        acc[i][j] = __builtin_amdgcn_mfma_f32_16x16x32_bf16(ah[i], bh[j], acc[i][j], 0, 0, 0);
        acc[i][j] = __builtin_amdgcn_mfma_f32_16x16x32_bf16(al[i], bh[j], acc[i][j], 0, 0, 0);
        acc[i][j] = __builtin_amdgcn_mfma_f32_16x16x32_bf16(ah[i], bl[j], acc[i][j], 0, 0, 0);
      }
  }

  // ---- epilogue: C/D layout col=lane&15, row=(lane>>4)*4+reg ----
  if(pooled == nullptr){
#pragma unroll
    for(int j = 0; j < 4; j++){
      int col = wn * 64 + j * 16 + lm;
      float bv = bias[col];
#pragma unroll
      for(int i = 0; i < 4; i++){
#pragma unroll
        for(int reg = 0; reg < 4; reg++){
          int row = bm + wm * 64 + i * 16 + lg * 4 + reg;
          if(row < M){
            float v = acc[i][j][reg] + bv;
            v = v > 0.f ? v : NEG_SLOPE * v;
            unsigned short h, l;
            split2_bf16(v, h, l);
            Hhi[(long long)row * C + col] = (short)h;
            Hlo[(long long)row * C + col] = (short)l;
          }
        }
      }
    }
  }else{
    // fused global-max-pool: reg-quad covers 4 consecutive rows
#pragma unroll
    for(int i = 0; i < 4; i++){
      int row0 = bm + wm * 64 + i * 16 + lg * 4;
      if(row0 >= M) continue;
      bool whole = (row0 + 3 < M);
      int g0 = batch[row0];
      bool same = whole && (batch[row0 + 3] == g0);
#pragma unroll
      for(int j = 0; j < 4; j++){
        int col = wn * 64 + j * 16 + lm;
        float bv = bias[col];
        float v0 = acc[i][j][0] + bv; v0 = v0 > 0.f ? v0 : NEG_SLOPE * v0;
        float v1 = acc[i][j][1] + bv; v1 = v1 > 0.f ? v1 : NEG_SLOPE * v1;
        float v2 = acc[i][j][2] + bv; v2 = v2 > 0.f ? v2 : NEG_SLOPE * v2;
        float v3 = acc[i][j][3] + bv; v3 = v3 > 0.f ? v3 : NEG_SLOPE * v3;
        if(same){
          float m01 = fmaxf(v0, v1), m23 = fmaxf(v2, v3);
          atomicMax(&pooled[g0 * C + col], fmap(fmaxf(m01, m23)));
        }else{
          float vv[4] = {v0, v1, v2, v3};
#pragma unroll
          for(int reg = 0; reg < 4; reg++){
            int row = row0 + reg;
            if(row < M) atomicMax(&pooled[batch[row] * C + col], fmap(vv[reg]));
          }
        }
      }
    }
  }
}

__global__ void fc_kernel(const unsigned* __restrict__ pooled_u, const float* __restrict__ Wfc,
                          const float* __restrict__ bfc, float* __restrict__ out){
  int t = threadIdx.x;   // 0..127
  int g = t >> 1, o = t & 1;
  float s = bfc[o];
  for(int k = 0; k < C; k++)
    s += funmap(pooled_u[g * C + k]) * Wfc[k * 2 + o];
  out[g * 2 + o] = s;
}

extern "C" void kernel_launch(void* const* d_in, const int* in_sizes, int n_in,
                              void* d_out, int out_size, void* d_ws, size_t ws_size,
                              hipStream_t stream) {
  const float* x    = (const float*)d_in[0];
  const int*   ei   = (const int*)d_in[1];
  const int*   batch= (const int*)d_in[2];
  const float* W1l  = (const float*)d_in[3];
  const float* b1   = (const float*)d_in[4];
  const float* W1r  = (const float*)d_in[5];
  const float* W2l  = (const float*)d_in[6];
  const float* b2   = (const float*)d_in[7];
  const float* W2r  = (const float*)d_in[8];
  const float* W3l  = (const float*)d_in[9];
  const float* b3   = (const float*)d_in[10];
  const float* W3r  = (const float*)d_in[11];
  const float* Wfc  = (const float*)d_in[12];
  const float* bfc  = (const float*)d_in[13];
  float* out = (float*)d_out;

  const int N = in_sizes[0] / C;   // 50000
  const int E = in_sizes[1] / 2;   // 600000
  const int* srcv = ei;
  const int* dstv = ei + E;

  char* ws = (char*)d_ws;
  size_t off = 0;
  auto alloc = [&](size_t bytes) -> void* {
    void* p = ws + off;
    off += (bytes + 255) & ~(size_t)255;
    return p;
  };
  int*      deg    = (int*)alloc((size_t)N * 4);
  float*    inv_d  = (float*)alloc((size_t)N * 4);
  int*      incl   = (int*)alloc((size_t)N * 4);
  int*      bsum   = (int*)alloc((size_t)64 * 4);
  int*      boff   = (int*)alloc((size_t)64 * 4);
  int*      rows   = (int*)alloc((size_t)(N + 1) * 4);
  int*      cursor = (int*)alloc((size_t)N * 4);
  int*      csr    = (int*)alloc((size_t)E * 4);
  // bf16 hi/lo activation planes (x buffers reused for h2)
  short*    xhi    = (short*)alloc((size_t)N * C * 2);
  short*    xlo    = (short*)alloc((size_t)N * C * 2);
  short*    mhi    = (short*)alloc((size_t)N * C * 2);
  short*    mlo    = (short*)alloc((size_t)N * C * 2);
  short*    h1hi   = (short*)alloc((size_t)N * C * 2);
  short*    h1lo   = (short*)alloc((size_t)N * C * 2);
  short*    B1     = (short*)alloc((size_t)2 * 2 * C * C * 2);
  short*    B2     = (short*)alloc((size_t)2 * 2 * C * C * 2);
  short*    B3     = (short*)alloc((size_t)2 * 2 * C * C * 2);
  unsigned* pooled = (unsigned*)alloc((size_t)NGRAPH * C * 4);

  hipMemsetAsync(deg, 0, (size_t)N * 4, stream);
  hipMemsetAsync(cursor, 0, (size_t)N * 4, stream);
  hipMemsetAsync(pooled, 0, (size_t)NGRAPH * C * 4, stream);

  const int nb = (N + 1023) / 1024;   // 49
  split_plane<<<(N * C / 2 + 255) / 256, 256, 0, stream>>>(x, xhi, xlo, N * C);
  deg_kernel<<<(E + 255) / 256, 256, 0, stream>>>(dstv, deg, E);
  scan_block<<<nb, 1024, 0, stream>>>(deg, incl, bsum, N);
  scan_bsum<<<1, 64, 0, stream>>>(bsum, boff, nb);
  finalize_rows<<<(N + 255) / 256, 256, 0, stream>>>(incl, deg, boff, rows, inv_d, N, E);
  csr_fill_kernel<<<(E + 255) / 256, 256, 0, stream>>>(srcv, dstv, rows, cursor, csr, E);

  pack_kernel<<<(2 * C * C + 255) / 256, 256, 0, stream>>>(W1l, W1r, B1);
  pack_kernel<<<(2 * C * C + 255) / 256, 256, 0, stream>>>(W2l, W2r, B2);
  pack_kernel<<<(2 * C * C + 255) / 256, 256, 0, stream>>>(W3l, W3r, B3);

  int gemmblocks = (N + 127) / 128;
  int aggblocks = (N + 3) / 4;   // 4 nodes (waves) per 256-thread block

  // layer 1: x -> h1
  agg_csr_bf16<<<aggblocks, 256, 0, stream>>>(xhi, csr, rows, inv_d, mhi, mlo, N);
  gemm_mfma2<<<gemmblocks, 256, 0, stream>>>(mhi, mlo, xhi, xlo, B1, b1,
                                             h1hi, h1lo, N, nullptr, nullptr);
  // layer 2: h1 -> h2 (stored into x buffers)
  agg_csr_bf16<<<aggblocks, 256, 0, stream>>>(h1hi, csr, rows, inv_d, mhi, mlo, N);
  gemm_mfma2<<<gemmblocks, 256, 0, stream>>>(mhi, mlo, h1hi, h1lo, B2, b2,
                                             xhi, xlo, N, nullptr, nullptr);
  // layer 3: h2 -> pooled (fused global-max-pool epilogue)
  agg_csr_bf16<<<aggblocks, 256, 0, stream>>>(xhi, csr, rows, inv_d, mhi, mlo, N);
  gemm_mfma2<<<gemmblocks, 256, 0, stream>>>(mhi, mlo, xhi, xlo, B3, b3,
                                             nullptr, nullptr, N, batch, pooled);

  fc_kernel<<<1, 128, 0, stream>>>(pooled, Wfc, bfc, out);
}